// Round 1
// baseline (10.755 us; speedup 1.0000x reference)
//
#include <hip/hip_runtime.h>
#include <hip/hip_bf16.h>

// Soft-codebook quantization, t-Student kernel, STE forward.
// Forward output is numerically exactly `hard` = nearest codebook value
// (codebook = integers -7..8), ties toward the LOWER value (argmax first-index).
// hard = clamp(ceil(x - 0.5), -7, 8). Pure memory-bound elementwise op.

__device__ __forceinline__ float quant1(float v) {
    // ceil(v - 0.5) == round-to-nearest with ties DOWN (exact in fp32 for |v|<2^23)
    float r = ceilf(v - 0.5f);
    r = fmaxf(-7.0f, fminf(8.0f, r));
    return r + 0.0f;  // normalize -0.0 -> +0.0
}

__global__ void __launch_bounds__(256) quant_kernel(const float4* __restrict__ x,
                                                    float4* __restrict__ out,
                                                    int n4) {
    int i = blockIdx.x * blockDim.x + threadIdx.x;
    int stride = gridDim.x * blockDim.x;
    for (; i < n4; i += stride) {
        float4 v = x[i];
        float4 r;
        r.x = quant1(v.x);
        r.y = quant1(v.y);
        r.z = quant1(v.z);
        r.w = quant1(v.w);
        out[i] = r;
    }
}

extern "C" void kernel_launch(void* const* d_in, const int* in_sizes, int n_in,
                              void* d_out, int out_size, void* d_ws, size_t ws_size,
                              hipStream_t stream) {
    const float* x = (const float*)d_in[0];
    float* out = (float*)d_out;
    int n = out_size;          // 16*64*64*64 = 4194304, divisible by 4
    int n4 = n / 4;            // 1048576 float4 elements
    int block = 256;
    int grid = n4 / block;     // 4096 blocks, one float4 per thread
    if (grid * block < n4) grid += 1;
    quant_kernel<<<grid, block, 0, stream>>>((const float4*)x, (float4*)out, n4);
}